// Round 7
// baseline (1649.301 us; speedup 1.0000x reference)
//
#include <hip/hip_runtime.h>
#include <math.h>

typedef float f32x2 __attribute__((ext_vector_type(2)));
typedef float f32x4 __attribute__((ext_vector_type(4)));

#define NPARTS 20
#define BATCH  2048
#define TOTALV 991
#define NEPS   9

#define LOG2E 1.4426950408889634f
#define LN2   0.6931471805599453f

__constant__ int   c_start[NPARTS] = {0,45,106,149,194,286,320,361,423,467,511,569,611,651,711,752,787,851,879,929};
__constant__ int   c_n[NPARTS]     = {45,61,43,45,92,34,41,62,44,44,58,42,40,60,41,35,64,28,50,62};
__constant__ float c_eps[NEPS]     = {64.0f,16.0f,4.0f,1.0f,0.25f,0.0625f,0.015625f,0.00390625f,0.0025f};

// 4 wave-slots, parts bin-packed (R=4 rows/lane, h=ceil(n/4) lanes/part):
//  slot0: p4(92) p7(62) p19(62) p15(35)             rows 251
//  slot1: p16(64) p1(61) p13(60) p12(40) p17(28)    rows 253
//  slot2: p10(58) p18(50) p0(45) p3(45) p8(44)      rows 242
//  slot3: p9(44) p2(43) p11(42) p6(41) p14(41) p5(34) rows 245
// Block = 128 thr = 2 waves; pair 0 -> slots {0,3}, pair 1 -> slots {1,2}.
__constant__ int c_w_np[4]       = {4,5,5,6};
__constant__ int c_w_part[4][6]  = {{4,7,19,15,0,0},{16,1,13,12,17,0},{10,18,0,3,8,0},{9,2,11,6,14,5}};
__constant__ int c_w_lane0[4][7] = {{0,23,39,55,64,64,64},{0,16,32,47,57,64,64},{0,15,28,40,52,63,64},{0,11,22,33,44,55,64}};
__constant__ int c_w_tb[4][6]    = {{0,92,154,216,0,0},{0,64,125,185,225,0},{0,58,108,153,198,0},{0,44,87,129,170,211}};

#define NROWS 496   // max(251+245, 253+242)

static __device__ __forceinline__ f32x2 sp(float v){ f32x2 r; r.x=v; r.y=v; return r; }
static __device__ __forceinline__ float gc(f32x2 v, int c){ return c ? v.y : v.x; }

// VOP3P packed-f32 (CDNA set: pk_fma/pk_mul/pk_add/pk_mov ONLY — no pk_max!).
// ALL operands are 64-bit VGPR pairs; scalar broadcast via per-operand
// half-selects (op_sel = low-result half, op_sel_hi = high-result half).
#define PKF_LH(d,a,b,c) asm("v_pk_fma_f32 %0, %1, %2, %3 op_sel:[0,0,1] op_sel_hi:[1,0,1]" : "=v"(d) : "v"(a), "v"(b), "v"(c))  // d = a*lo(b)+hi(c)
#define PKF_LL(d,a,b,c) asm("v_pk_fma_f32 %0, %1, %2, %3 op_sel:[0,0,0] op_sel_hi:[1,0,0]" : "=v"(d) : "v"(a), "v"(b), "v"(c))  // d = a*lo(b)+lo(c)
#define PKF_HP(d,a,b,c) asm("v_pk_fma_f32 %0, %1, %2, %3 op_sel:[0,1,0] op_sel_hi:[1,1,1]" : "=v"(d) : "v"(a), "v"(b), "v"(c))  // d = a*hi(b)+c
#define PKF_LP(d,a,b,c) asm("v_pk_fma_f32 %0, %1, %2, %3 op_sel:[0,0,0] op_sel_hi:[1,0,1]" : "=v"(d) : "v"(a), "v"(b), "v"(c))  // d = a*lo(b)+c
#define PKSUB(d,w,m)    asm("v_pk_add_f32 %0, %1, %2 neg_lo:[0,1] neg_hi:[0,1]" : "=v"(d) : "v"(w), "v"(m))  // d = w - m
// scalar max on halves (v_max_f32 on sub-registers; no packed f32 max on CDNA)
#define SMAX(m,w)       do { (m).x = fmaxf((m).x,(w).x); (m).y = fmaxf((m).y,(w).y); } while(0)

// Tables: sX[k]=(sc*x_k, fterm_k), sY[k]=(sc*y_k, gterm_k), sT[k]=(pxterm_k, pyterm_k),
// *term_k = v_k*sc + a_k + lA, a_k = -0.5*|.|^2*sc. Row-side ax_i cancels in exp2,
// re-added at finalize. Each wave uses only its own LDS region -> zero barriers.
__global__ __launch_bounds__(128) void sinkhorn_kernel(
    const float* __restrict__ pred, const float* __restrict__ pc,
    float* __restrict__ partial)
{
    __shared__ float4 sX[NROWS];
    __shared__ float4 sY[NROWS];
    __shared__ float2 sT[NROWS];

    const int bid  = blockIdx.x;
    const int b    = bid >> 1;
    const int pair = bid & 1;
    const int wv   = threadIdx.x >> 6;
    const int lane = threadIdx.x & 63;
    const int w    = pair ? (wv ? 2 : 1) : (wv ? 3 : 0);          // slot id
    const int rb   = wv ? (pair ? 253 : 251) : 0;                  // LDS region base

    int pj = -1;
    const int np = c_w_np[w];
    #pragma unroll
    for (int j = 0; j < 6; ++j)
        if (j < np && lane >= c_w_lane0[w][j] && lane < c_w_lane0[w][j+1]) pj = j;
    const bool lact = (pj >= 0);
    const int jj   = lact ? pj : 0;
    const int part = c_w_part[w][jj];
    const int st   = c_start[part];
    const int n    = lact ? c_n[part] : 0;
    const int h    = (n + 3) >> 2;
    const int r0   = lact ? (lane - c_w_lane0[w][jj]) : 0;
    const int tb   = rb + c_w_tb[w][jj];

    f32x2 X0[2],X1[2],X2[2],Y0[2],Y1[2],Y2[2];
    float xh[4], yh[4];
    bool ra[4];
    #pragma unroll
    for (int j=0;j<4;++j) {
        const int r = r0 + j*h;
        ra[j] = lact && (r < n);
        float a0=0.f,a1=0.f,a2=0.f,b0=0.f,b1=0.f,b2=0.f;
        if (ra[j]) {
            const float* xp = pred + ((size_t)b*TOTALV + st + r)*3;
            const float* yp = pc   + ((size_t)b*TOTALV + st + r)*3;
            a0=xp[0]; a1=xp[1]; a2=xp[2];
            b0=yp[0]; b1=yp[1]; b2=yp[2];
        }
        const int p=j>>1;
        if ((j&1)==0) { X0[p].x=a0; X1[p].x=a1; X2[p].x=a2; Y0[p].x=b0; Y1[p].x=b1; Y2[p].x=b2; }
        else          { X0[p].y=a0; X1[p].y=a1; X2[p].y=a2; Y0[p].y=b0; Y1[p].y=b1; Y2[p].y=b2; }
        xh[j] = -0.5f*(a0*a0+a1*a1+a2*a2);
        yh[j] = -0.5f*(b0*b0+b1*b1+b2*b2);
    }
    const float lA = lact ? -log2f((float)n) : 0.f;
    float f[4]={0,0,0,0}, g[4]={0,0,0,0}, px[4]={0,0,0,0}, py[4]={0,0,0,0};
    float ax[4], ay[4];

    for (int it=0; it<NEPS; ++it) {
        const float eps = c_eps[it];
        const float sc  = LOG2E/eps;
        const float ce  = -eps*LN2;
        #pragma unroll
        for (int j=0;j<4;++j) { ax[j]=xh[j]*sc; ay[j]=yh[j]*sc; }

        // build tables (pre-update f,g,px,py: matches reference order).
        // Same-wave DS ops are program-ordered; wave-private region; no barrier.
        #pragma unroll
        for (int j=0;j<4;++j) if (ra[j]) {
            const int p=j>>1, c=j&1;
            const int tr = tb + r0 + j*h;
            sX[tr] = make_float4(gc(X0[p],c)*sc, gc(X1[p],c)*sc, gc(X2[p],c)*sc, fmaf(f[j],  sc, ax[j]+lA));
            sY[tr] = make_float4(gc(Y0[p],c)*sc, gc(Y1[p],c)*sc, gc(Y2[p],c)*sc, fmaf(g[j],  sc, ay[j]+lA));
            sT[tr] = make_float2(fmaf(px[j], sc, ax[j]+lA), fmaf(py[j], sc, ay[j]+lA));
        }

        f32x2 MF[2],MG[2],MP[2],MQ[2];
        #pragma unroll
        for (int p=0;p<2;++p){ MF[p]=sp(-INFINITY); MG[p]=sp(-INFINITY); MP[p]=sp(-INFINITY); MQ[p]=sp(-INFINITY); }

        // pass 1: max
        #pragma unroll 2
        for (int k=0; k<n; ++k) {
            const f32x4 XA = *reinterpret_cast<const f32x4*>(&sX[tb+k]);
            const f32x4 YA = *reinterpret_cast<const f32x4*>(&sY[tb+k]);
            const f32x2 TT = *reinterpret_cast<const f32x2*>(&sT[tb+k]);
            const f32x2 XAxy = XA.xy, XAzw = XA.zw, YAxy = YA.xy, YAzw = YA.zw;
            #pragma unroll
            for (int p=0;p<2;++p) {
                f32x2 wf,wq,wg,wp;
                PKF_LH(wf, X2[p], YAzw, YAzw); PKF_HP(wf, X1[p], YAxy, wf); PKF_LP(wf, X0[p], YAxy, wf);
                PKF_LH(wq, Y2[p], YAzw, TT  ); PKF_HP(wq, Y1[p], YAxy, wq); PKF_LP(wq, Y0[p], YAxy, wq);
                PKF_LH(wg, Y2[p], XAzw, XAzw); PKF_HP(wg, Y1[p], XAxy, wg); PKF_LP(wg, Y0[p], XAxy, wg);
                PKF_LL(wp, X2[p], XAzw, TT  ); PKF_HP(wp, X1[p], XAxy, wp); PKF_LP(wp, X0[p], XAxy, wp);
                SMAX(MF[p], wf); SMAX(MQ[p], wq); SMAX(MG[p], wg); SMAX(MP[p], wp);
            }
        }

        // pass 2: exp2-sum
        f32x2 SF[2],SG[2],SP[2],SQ[2];
        #pragma unroll
        for (int p=0;p<2;++p){ SF[p]=sp(0.f); SG[p]=sp(0.f); SP[p]=sp(0.f); SQ[p]=sp(0.f); }
        #pragma unroll 2
        for (int k=0; k<n; ++k) {
            const f32x4 XA = *reinterpret_cast<const f32x4*>(&sX[tb+k]);
            const f32x4 YA = *reinterpret_cast<const f32x4*>(&sY[tb+k]);
            const f32x2 TT = *reinterpret_cast<const f32x2*>(&sT[tb+k]);
            const f32x2 XAxy = XA.xy, XAzw = XA.zw, YAxy = YA.xy, YAzw = YA.zw;
            #pragma unroll
            for (int p=0;p<2;++p) {
                f32x2 wf,wq,wg,wp,d;
                PKF_LH(wf, X2[p], YAzw, YAzw); PKF_HP(wf, X1[p], YAxy, wf); PKF_LP(wf, X0[p], YAxy, wf);
                PKF_LH(wq, Y2[p], YAzw, TT  ); PKF_HP(wq, Y1[p], YAxy, wq); PKF_LP(wq, Y0[p], YAxy, wq);
                PKF_LH(wg, Y2[p], XAzw, XAzw); PKF_HP(wg, Y1[p], XAxy, wg); PKF_LP(wg, Y0[p], XAxy, wg);
                PKF_LL(wp, X2[p], XAzw, TT  ); PKF_HP(wp, X1[p], XAxy, wp); PKF_LP(wp, X0[p], XAxy, wp);
                PKSUB(d, wf, MF[p]); SF[p].x += __builtin_amdgcn_exp2f(d.x); SF[p].y += __builtin_amdgcn_exp2f(d.y);
                PKSUB(d, wq, MQ[p]); SQ[p].x += __builtin_amdgcn_exp2f(d.x); SQ[p].y += __builtin_amdgcn_exp2f(d.y);
                PKSUB(d, wg, MG[p]); SG[p].x += __builtin_amdgcn_exp2f(d.x); SG[p].y += __builtin_amdgcn_exp2f(d.y);
                PKSUB(d, wp, MP[p]); SP[p].x += __builtin_amdgcn_exp2f(d.x); SP[p].y += __builtin_amdgcn_exp2f(d.y);
            }
        }

        #pragma unroll
        for (int j=0;j<4;++j) {
            const int p=j>>1, c=j&1;
            f[j]  = 0.5f*(f[j]  + ce*(ax[j] + gc(MF[p],c) + __builtin_amdgcn_logf(gc(SF[p],c))));
            g[j]  = 0.5f*(g[j]  + ce*(ay[j] + gc(MG[p],c) + __builtin_amdgcn_logf(gc(SG[p],c))));
            px[j] = 0.5f*(px[j] + ce*(ax[j] + gc(MP[p],c) + __builtin_amdgcn_logf(gc(SP[p],c))));
            py[j] = 0.5f*(py[j] + ce*(ay[j] + gc(MQ[p],c) + __builtin_amdgcn_logf(gc(SQ[p],c))));
        }
    }

    float d = 0.f;
    #pragma unroll
    for (int j=0;j<4;++j) if (ra[j]) d += (f[j]-px[j]) + (g[j]-py[j]);
    if (lact) d *= 1.0f/(float)n;
    #pragma unroll
    for (int o=32;o>0;o>>=1) d += __shfl_down(d, o, 64);
    if (lane==0) partial[(bid<<1)+wv] = d * (1.0f/(float)BATCH);
}

__global__ __launch_bounds__(1024) void reduce_kernel(
    const float* __restrict__ partial, float* __restrict__ out, int nb)
{
    const int t = threadIdx.x;
    double acc = 0.0;
    for (int i=t; i<nb; i+=blockDim.x) acc += (double)partial[i];
    #pragma unroll
    for (int o=32; o>0; o>>=1) acc += __shfl_down(acc, o, 64);
    __shared__ double ws[16];
    if ((t & 63) == 0) ws[t >> 6] = acc;
    __syncthreads();
    if (t == 0) {
        double tot = 0.0;
        for (int v=0; v<1024/64; ++v) tot += ws[v];
        out[0] = (float)tot;
    }
}

extern "C" void kernel_launch(void* const* d_in, const int* in_sizes, int n_in,
                              void* d_out, int out_size, void* d_ws, size_t ws_size,
                              hipStream_t stream) {
    const float* pred = (const float*)d_in[0];
    const float* pc   = (const float*)d_in[1];
    float* partial = (float*)d_ws;                  // BATCH*4 floats = 32 KB
    float* out     = (float*)d_out;
    sinkhorn_kernel<<<BATCH*2, 128, 0, stream>>>(pred, pc, partial);
    reduce_kernel<<<1, 1024, 0, stream>>>(partial, out, BATCH*4);
}

// Round 10
// 1400.597 us; speedup vs baseline: 1.1776x; 1.1776x over previous
//
#include <hip/hip_runtime.h>
#include <math.h>

#define NPARTS 20
#define BATCH  2048
#define TOTALV 991
#define NEPS   9

#define LOG2E 1.4426950408889634f
#define LN2   0.6931471805599453f
#define NEGBIG -1.0e30f

__constant__ int   c_start[NPARTS] = {0,45,106,149,194,286,320,361,423,467,511,569,611,651,711,752,787,851,879,929};
__constant__ int   c_n[NPARTS]     = {45,61,43,45,92,34,41,62,44,44,58,42,40,60,41,35,64,28,50,62};
__constant__ float c_eps[NEPS]     = {64.0f,16.0f,4.0f,1.0f,0.25f,0.0625f,0.015625f,0.00390625f,0.0025f};

// 4 wave-slots, parts bin-packed (R=4 rows/lane, h=ceil(n/4) lanes/part).
// Tables padded to 4h rows/part (pads: coords=0, terms=-1e30 -> exp2 -> 0).
//  slot0: p4(h23) p7(16) p19(16) p15(9)    -> 256 rows
//  slot1: p16(16) p1(16) p13(15) p12(10) p17(7) -> 256
//  slot2: p10(15) p18(13) p0(12) p3(12) p8(11)  -> 252
//  slot3: p9(11) p2(11) p11(11) p6(11) p14(11) p5(9) -> 256
// Block = 128 thr = 2 waves; pair0 -> slots {0,3}, pair1 -> slots {1,2}; region = wv*256.
__constant__ int c_w_np[4]       = {4,5,5,6};
__constant__ int c_w_part[4][6]  = {{4,7,19,15,0,0},{16,1,13,12,17,0},{10,18,0,3,8,0},{9,2,11,6,14,5}};
__constant__ int c_w_lane0[4][7] = {{0,23,39,55,64,64,64},{0,16,32,47,57,64,64},{0,15,28,40,52,63,64},{0,11,22,33,44,55,64}};
__constant__ int c_w_tb[4][6]    = {{0,92,156,220,0,0},{0,64,128,188,228,0},{0,60,112,160,208,0},{0,44,88,132,176,220}};

#define NROWS 512

// Online-lse chunk update for one stream: 4 w's, chunk max, one rescale.
#define STREAM_UPDATE(A0,A1,A2, C0,C1A,C2A, TT, M, S) do { \
  const float w0_ = fmaf(A0, C0[0], fmaf(A1, C1A[0], fmaf(A2, C2A[0], TT[0]))); \
  const float w1_ = fmaf(A0, C0[1], fmaf(A1, C1A[1], fmaf(A2, C2A[1], TT[1]))); \
  const float w2_ = fmaf(A0, C0[2], fmaf(A1, C1A[2], fmaf(A2, C2A[2], TT[2]))); \
  const float w3_ = fmaf(A0, C0[3], fmaf(A1, C1A[3], fmaf(A2, C2A[3], TT[3]))); \
  const float mc_ = fmaxf(fmaxf(w0_, w1_), fmaxf(w2_, w3_)); \
  const float mn_ = fmaxf(M, mc_); \
  const float rr_ = __builtin_amdgcn_exp2f(M - mn_); \
  const float e0_ = __builtin_amdgcn_exp2f(w0_ - mn_); \
  const float e1_ = __builtin_amdgcn_exp2f(w1_ - mn_); \
  const float e2_ = __builtin_amdgcn_exp2f(w2_ - mn_); \
  const float e3_ = __builtin_amdgcn_exp2f(w3_ - mn_); \
  S = fmaf(S, rr_, (e0_ + e1_) + (e2_ + e3_)); \
  M = mn_; \
} while(0)

// Tables: sC1[k]=(x0,x1,x2,y0) sC2[k]=(y1,y2) static; sS[k]=(tf,tg,tp,tq) per-eps,
// t*_k = sc*(v_k + colnorm_k) + lA. Row-side -0.5|.|^2*sc cancels in exp2, added at
// finalize. Column coords scaled by sc at chunk load; row regs stay raw.
// Wave-private LDS regions + same-wave DS program order -> zero barriers.
__global__ __launch_bounds__(128) void sinkhorn_kernel(
    const float* __restrict__ pred, const float* __restrict__ pc,
    float* __restrict__ partial)
{
    __shared__ float4 sC1[NROWS];
    __shared__ float2 sC2[NROWS];
    __shared__ float4 sS[NROWS];

    const int bid  = blockIdx.x;
    const int b    = bid >> 1;
    const int pair = bid & 1;
    const int wv   = threadIdx.x >> 6;
    const int lane = threadIdx.x & 63;
    const int w    = pair ? (wv ? 2 : 1) : (wv ? 3 : 0);   // slot id
    const int rb   = wv << 8;                               // LDS region base

    int pj = -1;
    const int np = c_w_np[w];
    #pragma unroll
    for (int j = 0; j < 6; ++j)
        if (j < np && lane >= c_w_lane0[w][j] && lane < c_w_lane0[w][j+1]) pj = j;
    const bool lact = (pj >= 0);
    const int jj   = lact ? pj : 0;
    const int part = c_w_part[w][jj];
    const int st   = c_start[part];
    const int n    = lact ? c_n[part] : 0;
    const int h    = (n + 3) >> 2;          // chunks (and lanes) per part
    const int r0   = lact ? (lane - c_w_lane0[w][jj]) : 0;
    const int tb   = rb + c_w_tb[w][jj];

    float x0r[4],x1r[4],x2r[4],y0r[4],y1r[4],y2r[4],xh[4],yh[4];
    bool ra[4];
    #pragma unroll
    for (int j=0;j<4;++j) {
        const int r = r0 + j*h;
        ra[j] = lact && (r < n);
        float a0=0.f,a1=0.f,a2=0.f,b0=0.f,b1=0.f,b2=0.f;
        if (ra[j]) {
            const float* xp = pred + ((size_t)b*TOTALV + st + r)*3;
            const float* yp = pc   + ((size_t)b*TOTALV + st + r)*3;
            a0=xp[0]; a1=xp[1]; a2=xp[2];
            b0=yp[0]; b1=yp[1]; b2=yp[2];
        }
        x0r[j]=a0; x1r[j]=a1; x2r[j]=a2;
        y0r[j]=b0; y1r[j]=b1; y2r[j]=b2;
        xh[j] = -0.5f*(a0*a0+a1*a1+a2*a2);
        yh[j] = -0.5f*(b0*b0+b1*b1+b2*b2);
    }
    // static coord tables (pads get zeros) — written once
    #pragma unroll
    for (int j=0;j<4;++j) if (lact) {
        const int tr = tb + r0 + j*h;
        sC1[tr] = make_float4(x0r[j], x1r[j], x2r[j], y0r[j]);
        sC2[tr] = make_float2(y1r[j], y2r[j]);
    }

    const float lA = lact ? -log2f((float)n) : 0.f;
    float f[4]={0,0,0,0}, g[4]={0,0,0,0}, px[4]={0,0,0,0}, py[4]={0,0,0,0};

    #pragma unroll 1
    for (int it=0; it<NEPS; ++it) {
        const float eps = c_eps[it];
        const float sc  = LOG2E/eps;
        const float ce  = -eps*LN2;

        // per-eps terms (pre-update f,g,px,py: matches reference order)
        #pragma unroll
        for (int j=0;j<4;++j) if (lact) {
            const int tr = tb + r0 + j*h;
            if (ra[j])
                sS[tr] = make_float4(fmaf(sc, g[j]  + yh[j], lA),
                                     fmaf(sc, f[j]  + xh[j], lA),
                                     fmaf(sc, px[j] + xh[j], lA),
                                     fmaf(sc, py[j] + yh[j], lA));
            else
                sS[tr] = make_float4(NEGBIG, NEGBIG, NEGBIG, NEGBIG);
        }

        float mF[4],mG[4],mP[4],mQ[4],sF[4],sG[4],sP[4],sQ[4];
        #pragma unroll
        for (int j=0;j<4;++j) {
            mF[j]=-INFINITY; mG[j]=-INFINITY; mP[j]=-INFINITY; mQ[j]=-INFINITY;
            sF[j]=0.f; sG[j]=0.f; sP[j]=0.f; sQ[j]=0.f;
        }

        #pragma unroll 1
        for (int c=0; c<h; ++c) {
            const int row = tb + (c<<2);
            float cx0[4],cx1[4],cx2[4],cy0[4],cy1[4],cy2[4],tf[4],tg[4],tp[4],tq[4];
            #pragma unroll
            for (int kk=0;kk<4;++kk) {
                const float4 a = sC1[row+kk];
                const float2 c2 = sC2[row+kk];
                const float4 t = sS[row+kk];
                cx0[kk]=a.x*sc; cx1[kk]=a.y*sc; cx2[kk]=a.z*sc;
                cy0[kk]=a.w*sc; cy1[kk]=c2.x*sc; cy2[kk]=c2.y*sc;
                tf[kk]=t.x; tg[kk]=t.y; tp[kk]=t.z; tq[kk]=t.w;
            }
            #pragma unroll
            for (int j=0;j<4;++j) {
                STREAM_UPDATE(x0r[j],x1r[j],x2r[j], cy0,cy1,cy2, tf, mF[j], sF[j]); // ft
                STREAM_UPDATE(y0r[j],y1r[j],y2r[j], cx0,cx1,cx2, tg, mG[j], sG[j]); // gt
                STREAM_UPDATE(x0r[j],x1r[j],x2r[j], cx0,cx1,cx2, tp, mP[j], sP[j]); // px
                STREAM_UPDATE(y0r[j],y1r[j],y2r[j], cy0,cy1,cy2, tq, mQ[j], sQ[j]); // py
            }
        }

        if (lact) {
            #pragma unroll
            for (int j=0;j<4;++j) {
                const float ax = xh[j]*sc, ay = yh[j]*sc;
                f[j]  = 0.5f*(f[j]  + ce*(ax + mF[j] + __builtin_amdgcn_logf(sF[j])));
                g[j]  = 0.5f*(g[j]  + ce*(ay + mG[j] + __builtin_amdgcn_logf(sG[j])));
                px[j] = 0.5f*(px[j] + ce*(ax + mP[j] + __builtin_amdgcn_logf(sP[j])));
                py[j] = 0.5f*(py[j] + ce*(ay + mQ[j] + __builtin_amdgcn_logf(sQ[j])));
            }
        }
    }

    float d = 0.f;
    #pragma unroll
    for (int j=0;j<4;++j) if (ra[j]) d += (f[j]-px[j]) + (g[j]-py[j]);
    if (lact) d *= 1.0f/(float)n;
    #pragma unroll
    for (int o=32;o>0;o>>=1) d += __shfl_down(d, o, 64);
    if (lane==0) partial[(bid<<1)+wv] = d * (1.0f/(float)BATCH);
}

__global__ __launch_bounds__(1024) void reduce_kernel(
    const float* __restrict__ partial, float* __restrict__ out, int nb)
{
    const int t = threadIdx.x;
    double acc = 0.0;
    for (int i=t; i<nb; i+=blockDim.x) acc += (double)partial[i];
    #pragma unroll
    for (int o=32; o>0; o>>=1) acc += __shfl_down(acc, o, 64);
    __shared__ double ws[16];
    if ((t & 63) == 0) ws[t >> 6] = acc;
    __syncthreads();
    if (t == 0) {
        double tot = 0.0;
        for (int v=0; v<1024/64; ++v) tot += ws[v];
        out[0] = (float)tot;
    }
}

extern "C" void kernel_launch(void* const* d_in, const int* in_sizes, int n_in,
                              void* d_out, int out_size, void* d_ws, size_t ws_size,
                              hipStream_t stream) {
    const float* pred = (const float*)d_in[0];
    const float* pc   = (const float*)d_in[1];
    float* partial = (float*)d_ws;                  // BATCH*4 floats = 32 KB
    float* out     = (float*)d_out;
    sinkhorn_kernel<<<BATCH*2, 128, 0, stream>>>(pred, pc, partial);
    reduce_kernel<<<1, 1024, 0, stream>>>(partial, out, BATCH*4);
}

// Round 11
// 1184.370 us; speedup vs baseline: 1.3926x; 1.1826x over previous
//
#include <hip/hip_runtime.h>
#include <math.h>

#define NPARTS 20
#define BATCH  2048
#define TOTALV 991
#define NEPS   9

#define LOG2E 1.4426950408889634f
#define LN2   0.6931471805599453f
#define NEGBIG -1.0e30f

__constant__ int   c_start[NPARTS] = {0,45,106,149,194,286,320,361,423,467,511,569,611,651,711,752,787,851,879,929};
__constant__ int   c_n[NPARTS]     = {45,61,43,45,92,34,41,62,44,44,58,42,40,60,41,35,64,28,50,62};
__constant__ float c_eps[NEPS]     = {64.0f,16.0f,4.0f,1.0f,0.25f,0.0625f,0.015625f,0.00390625f,0.0025f};

// 4 wave-slots, parts bin-packed (R=4 rows/lane, h=ceil(n/4) lanes/part).
// Region layout: part-row r at region offset r (r in [0,4h)); rows >= n are pads
// (coords 0, terms -1e30 -> exp2 -> 0; pads <= 3 so every chunk has a real row).
//  slot0: p4(h23) p7(16) p19(16) p15(9)         offs 0,92,156,220  (256)
//  slot1: p16(16) p1(16) p13(15) p12(10) p17(7) offs 0,64,128,188,228 (256)
//  slot2: p10(15) p18(13) p0(12) p3(12) p8(11)  offs 0,60,112,160,208 (252)
//  slot3: p9(11) p2(11) p11(11) p6(11) p14(11) p5(9) offs 0,44,88,132,176,220 (256)
// Block = 256 thr = 4 waves = one batch item; wave wv covers slot (wv+b)&3
// (rotation spreads the h=23 slot across SIMDs between blocks).
__constant__ int c_w_np[4]       = {4,5,5,6};
__constant__ int c_w_part[4][6]  = {{4,7,19,15,0,0},{16,1,13,12,17,0},{10,18,0,3,8,0},{9,2,11,6,14,5}};
__constant__ int c_w_lane0[4][7] = {{0,23,39,55,64,64,64},{0,16,32,47,57,64,64},{0,15,28,40,52,63,64},{0,11,22,33,44,55,64}};
__constant__ int c_w_tb[4][6]    = {{0,92,156,220,0,0},{0,64,128,188,228,0},{0,60,112,160,208,0},{0,44,88,132,176,220}};

#define NROWS 1024

// Online-lse chunk update for one stream: 4 w's, chunk max, one rescale.
#define STREAM_UPDATE(A0,A1,A2, C0,C1A,C2A, TT, M, S) do { \
  const float w0_ = fmaf(A0, C0[0], fmaf(A1, C1A[0], fmaf(A2, C2A[0], TT[0]))); \
  const float w1_ = fmaf(A0, C0[1], fmaf(A1, C1A[1], fmaf(A2, C2A[1], TT[1]))); \
  const float w2_ = fmaf(A0, C0[2], fmaf(A1, C1A[2], fmaf(A2, C2A[2], TT[2]))); \
  const float w3_ = fmaf(A0, C0[3], fmaf(A1, C1A[3], fmaf(A2, C2A[3], TT[3]))); \
  const float mc_ = fmaxf(fmaxf(w0_, w1_), fmaxf(w2_, w3_)); \
  const float mn_ = fmaxf(M, mc_); \
  const float rr_ = __builtin_amdgcn_exp2f(M - mn_); \
  const float e0_ = __builtin_amdgcn_exp2f(w0_ - mn_); \
  const float e1_ = __builtin_amdgcn_exp2f(w1_ - mn_); \
  const float e2_ = __builtin_amdgcn_exp2f(w2_ - mn_); \
  const float e3_ = __builtin_amdgcn_exp2f(w3_ - mn_); \
  S = fmaf(S, rr_, (e0_ + e1_) + (e2_ + e3_)); \
  M = mn_; \
} while(0)

// Fused pre-scaled per-eps tables (written each eps, scaling amortized out of
// the chunk loop): sA[r]=(sc*y0,sc*y1,sc*y2, tf), sB[r]=(sc*x0,sc*x1,sc*x2, tg),
// sC[r]=(tq, tp); tf=sc*(g+yh)+lA, tg=sc*(f+xh)+lA, tp=sc*(px+xh)+lA,
// tq=sc*(py+yh)+lA. Row-side -0.5|.|^2*sc cancels in exp2, re-added at finalize.
// Wave-private LDS regions + same-wave DS program order -> zero barriers.
__global__ __launch_bounds__(256, 3) void sinkhorn_kernel(
    const float* __restrict__ pred, const float* __restrict__ pc,
    float* __restrict__ partial)
{
    __shared__ float4 sA[NROWS];
    __shared__ float4 sB[NROWS];
    __shared__ float2 sC[NROWS];

    const int b    = blockIdx.x;
    const int wv   = threadIdx.x >> 6;
    const int lane = threadIdx.x & 63;
    const int w    = (wv + b) & 3;     // slot id (rotated per block)
    const int rb   = w << 8;           // LDS region base (by slot)

    int pj = -1;
    const int np = c_w_np[w];
    #pragma unroll
    for (int j = 0; j < 6; ++j)
        if (j < np && lane >= c_w_lane0[w][j] && lane < c_w_lane0[w][j+1]) pj = j;
    const bool lact = (pj >= 0);
    const int jj   = lact ? pj : 0;
    const int part = c_w_part[w][jj];
    const int st   = c_start[part];
    const int n    = lact ? c_n[part] : 0;
    const int h    = (n + 3) >> 2;          // chunks (and lanes) per part
    const int r0   = lact ? (lane - c_w_lane0[w][jj]) : 0;
    const int tb   = rb + c_w_tb[w][jj];

    float x0r[4],x1r[4],x2r[4],y0r[4],y1r[4],y2r[4],xh[4],yh[4];
    bool ra[4];
    #pragma unroll
    for (int j=0;j<4;++j) {
        const int r = r0 + j*h;
        ra[j] = lact && (r < n);
        float a0=0.f,a1=0.f,a2=0.f,b0=0.f,b1=0.f,b2=0.f;
        if (ra[j]) {
            const float* xp = pred + ((size_t)b*TOTALV + st + r)*3;
            const float* yp = pc   + ((size_t)b*TOTALV + st + r)*3;
            a0=xp[0]; a1=xp[1]; a2=xp[2];
            b0=yp[0]; b1=yp[1]; b2=yp[2];
        }
        x0r[j]=a0; x1r[j]=a1; x2r[j]=a2;
        y0r[j]=b0; y1r[j]=b1; y2r[j]=b2;
        xh[j] = -0.5f*(a0*a0+a1*a1+a2*a2);
        yh[j] = -0.5f*(b0*b0+b1*b1+b2*b2);
    }

    const float lA = lact ? -log2f((float)n) : 0.f;
    float f[4]={0,0,0,0}, g[4]={0,0,0,0}, px[4]={0,0,0,0}, py[4]={0,0,0,0};

    #pragma unroll 1
    for (int it=0; it<NEPS; ++it) {
        const float eps = c_eps[it];
        const float sc  = LOG2E/eps;
        const float ce  = -eps*LN2;

        // write fused scaled tables (pre-update f,g,px,py: matches reference order)
        #pragma unroll
        for (int j=0;j<4;++j) if (lact) {
            const int tr = tb + r0 + j*h;
            if (ra[j]) {
                sA[tr] = make_float4(y0r[j]*sc, y1r[j]*sc, y2r[j]*sc, fmaf(sc, g[j]  + yh[j], lA));
                sB[tr] = make_float4(x0r[j]*sc, x1r[j]*sc, x2r[j]*sc, fmaf(sc, f[j]  + xh[j], lA));
                sC[tr] = make_float2(fmaf(sc, py[j] + yh[j], lA), fmaf(sc, px[j] + xh[j], lA));
            } else {
                sA[tr] = make_float4(0.f, 0.f, 0.f, NEGBIG);
                sB[tr] = make_float4(0.f, 0.f, 0.f, NEGBIG);
                sC[tr] = make_float2(NEGBIG, NEGBIG);
            }
        }

        float mF[4],mG[4],mP[4],mQ[4],sF[4],sG[4],sP[4],sQ[4];
        #pragma unroll
        for (int j=0;j<4;++j) {
            mF[j]=-INFINITY; mG[j]=-INFINITY; mP[j]=-INFINITY; mQ[j]=-INFINITY;
            sF[j]=0.f; sG[j]=0.f; sP[j]=0.f; sQ[j]=0.f;
        }

        #pragma unroll 2
        for (int c=0; c<h; ++c) {
            const int row = tb + (c<<2);
            float cy0[4],cy1[4],cy2[4],cx0[4],cx1[4],cx2[4],tf[4],tg[4],tp[4],tq[4];
            #pragma unroll
            for (int kk=0;kk<4;++kk) {
                const float4 a4 = sA[row+kk];
                const float4 b4 = sB[row+kk];
                const float2 c2 = sC[row+kk];
                cy0[kk]=a4.x; cy1[kk]=a4.y; cy2[kk]=a4.z; tf[kk]=a4.w;
                cx0[kk]=b4.x; cx1[kk]=b4.y; cx2[kk]=b4.z; tg[kk]=b4.w;
                tq[kk]=c2.x; tp[kk]=c2.y;
            }
            #pragma unroll
            for (int j=0;j<4;++j) {
                STREAM_UPDATE(x0r[j],x1r[j],x2r[j], cy0,cy1,cy2, tf, mF[j], sF[j]); // ft
                STREAM_UPDATE(y0r[j],y1r[j],y2r[j], cx0,cx1,cx2, tg, mG[j], sG[j]); // gt
                STREAM_UPDATE(x0r[j],x1r[j],x2r[j], cx0,cx1,cx2, tp, mP[j], sP[j]); // px
                STREAM_UPDATE(y0r[j],y1r[j],y2r[j], cy0,cy1,cy2, tq, mQ[j], sQ[j]); // py
            }
        }

        if (lact) {
            #pragma unroll
            for (int j=0;j<4;++j) {
                const float ax = xh[j]*sc, ay = yh[j]*sc;
                f[j]  = 0.5f*(f[j]  + ce*(ax + mF[j] + __builtin_amdgcn_logf(sF[j])));
                g[j]  = 0.5f*(g[j]  + ce*(ay + mG[j] + __builtin_amdgcn_logf(sG[j])));
                px[j] = 0.5f*(px[j] + ce*(ax + mP[j] + __builtin_amdgcn_logf(sP[j])));
                py[j] = 0.5f*(py[j] + ce*(ay + mQ[j] + __builtin_amdgcn_logf(sQ[j])));
            }
        }
    }

    float d = 0.f;
    #pragma unroll
    for (int j=0;j<4;++j) if (ra[j]) d += (f[j]-px[j]) + (g[j]-py[j]);
    if (lact) d *= 1.0f/(float)n;
    #pragma unroll
    for (int o=32;o>0;o>>=1) d += __shfl_down(d, o, 64);
    if (lane==0) partial[(b<<2)+wv] = d * (1.0f/(float)BATCH);
}

__global__ __launch_bounds__(1024) void reduce_kernel(
    const float* __restrict__ partial, float* __restrict__ out, int nb)
{
    const int t = threadIdx.x;
    double acc = 0.0;
    for (int i=t; i<nb; i+=blockDim.x) acc += (double)partial[i];
    #pragma unroll
    for (int o=32; o>0; o>>=1) acc += __shfl_down(acc, o, 64);
    __shared__ double ws[16];
    if ((t & 63) == 0) ws[t >> 6] = acc;
    __syncthreads();
    if (t == 0) {
        double tot = 0.0;
        for (int v=0; v<1024/64; ++v) tot += ws[v];
        out[0] = (float)tot;
    }
}

extern "C" void kernel_launch(void* const* d_in, const int* in_sizes, int n_in,
                              void* d_out, int out_size, void* d_ws, size_t ws_size,
                              hipStream_t stream) {
    const float* pred = (const float*)d_in[0];
    const float* pc   = (const float*)d_in[1];
    float* partial = (float*)d_ws;                  // BATCH*4 floats = 32 KB
    float* out     = (float*)d_out;
    sinkhorn_kernel<<<BATCH, 256, 0, stream>>>(pred, pc, partial);
    reduce_kernel<<<1, 1024, 0, stream>>>(partial, out, BATCH*4);
}